// Round 9
// baseline (149.019 us; speedup 1.0000x reference)
//
#include <hip/hip_runtime.h>
#include <math.h>

#define NLIB 128
#define INFBITS 0x7F800000u

typedef float f32x4 __attribute__((ext_vector_type(4)));

static __device__ __forceinline__ int iclamp(int v, int lo, int hi) {
    return v < lo ? lo : (v > hi ? hi : v);
}

// ---------------------------------------------------------------------------
// Kernel 1: per-row squared distance ||z_lib[n]-z||^2 (128 blocks x 256 thr)
// + init of smin-bits buffers. (R5-proven)
// ---------------------------------------------------------------------------
__global__ __launch_bounds__(256)
void row_dist_kernel(const float* __restrict__ z, const float* __restrict__ z_lib,
                     float* __restrict__ dist2, unsigned* __restrict__ sb0,
                     unsigned* __restrict__ sb1, unsigned* __restrict__ sb2) {
    const int n = blockIdx.x;
    const int tid = threadIdx.x, wave = tid >> 6, lane = tid & 63;
    const int gid = n * 256 + tid;
    if (gid < 3136)      sb0[gid] = INFBITS;
    else if (gid < 3920) sb1[gid - 3136] = INFBITS;
    else if (gid < 4116) sb2[gid - 3920] = INFBITS;

    const f32x4 a = ((const f32x4*)(z_lib + (size_t)n * 1024))[tid];
    const f32x4 b = ((const f32x4*)z)[tid];
    f32x4 d = a - b;
    f32x4 s = d * d;
    float acc = s[0] + s[1] + s[2] + s[3];
    for (int off = 32; off > 0; off >>= 1) acc += __shfl_down(acc, off, 64);
    __shared__ float ws4[4];
    if (lane == 0) ws4[wave] = acc;
    __syncthreads();
    if (tid == 0) dist2[n] = ws4[0] + ws4[1] + ws4[2] + ws4[3];
}

// ---------------------------------------------------------------------------
// Kernel 2: rank-select k smallest -> idx[rank]=n, z_score. (R5-proven)
// ---------------------------------------------------------------------------
__global__ __launch_bounds__(128)
void select_kernel(const float* __restrict__ dist2, const int* __restrict__ kp,
                   float* __restrict__ zscore, int* __restrict__ idx) {
    __shared__ float d[NLIB];
    __shared__ float contrib[NLIB];
    const int tid = threadIdx.x;
    d[tid] = dist2[tid];
    __syncthreads();
    const int k = *kp;
    const float dd = d[tid];
    int rank = 0;
#pragma unroll 8
    for (int m = 0; m < NLIB; ++m) {
        const float dm = d[m];
        rank += (dm < dd || (dm == dd && m < tid)) ? 1 : 0;
    }
    if (rank < k) idx[rank] = tid;
    contrib[tid] = (rank < k) ? sqrtf(dd) : 0.f;
    __syncthreads();
    if (tid == 0) {
        float s = 0.f;
        for (int m = 0; m < NLIB; ++m) s += contrib[m];   // fixed order
        zscore[0] = s / (float)k;
    }
}

// ---------------------------------------------------------------------------
// Kernel 3: FUSED dist+min, XCD-byte-balanced 24-tile layout (R5-proven),
// now 4 n per block via channel-chunking: 8 fmap quads held in registers are
// reused across 4 lib streams (fmap HBM/L2 traffic /4, atomics /4). Channel
// accumulation order per thread unchanged (ascending) -> bitwise-identical
// sums. One LDS combine (fixed g-order), elementwise min over the 4 images,
// atomicMin(uint bits). No NT hints (regressed twice).
// CW = C/G = 64 for all levels; 8 chunks x 8 channels.
// ---------------------------------------------------------------------------
template <int C, int NQ, int QT>
static __device__ __forceinline__ void dist_min_level(const float* __restrict__ lib,
                                                      const float* __restrict__ fmap,
                                                      const int* __restrict__ img,
                                                      int qt, unsigned* __restrict__ sb,
                                                      f32x4 (* __restrict__ part)[256]) {
    constexpr int G  = 256 / QT;       // channel groups per block
    constexpr int CW = C / G;          // channels per thread (= 64)
    const int tid = threadIdx.x;
    const int ql  = tid & (QT - 1);
    const int g   = tid / QT;
    const int q   = qt * QT + ql;
    const int qc  = q < NQ ? q : NQ - 1;     // clamp: dup same-address loads
    const f32x4* __restrict__ fp = (const f32x4*)fmap + ((size_t)g * CW) * NQ + qc;
    const f32x4* lp[4];
#pragma unroll
    for (int j = 0; j < 4; ++j)
        lp[j] = (const f32x4*)lib + ((size_t)img[j] * C + g * CW) * NQ + qc;

    f32x4 acc0 = {}, acc1 = {}, acc2 = {}, acc3 = {};
#pragma unroll
    for (int cc = 0; cc < CW / 8; ++cc) {
        f32x4 f[8];
#pragma unroll
        for (int u = 0; u < 8; ++u) f[u] = fp[(size_t)(cc * 8 + u) * NQ];
#pragma unroll
        for (int u = 0; u < 8; ++u) {
            const size_t off = (size_t)(cc * 8 + u) * NQ;
            f32x4 d0 = lp[0][off] - f[u]; acc0 += d0 * d0;
            f32x4 d1 = lp[1][off] - f[u]; acc1 += d1 * d1;
            f32x4 d2 = lp[2][off] - f[u]; acc2 += d2 * d2;
            f32x4 d3 = lp[3][off] - f[u]; acc3 += d3 * d3;
        }
    }
    part[0][tid] = acc0;
    part[1][tid] = acc1;
    part[2][tid] = acc2;
    part[3][tid] = acc3;
    __syncthreads();
    if (tid < QT && q < NQ) {
        f32x4 s0 = part[0][tid], s1 = part[1][tid], s2 = part[2][tid], s3 = part[3][tid];
#pragma unroll
        for (int gg = 1; gg < G; ++gg) {            // fixed ascending g order
            s0 += part[0][gg * QT + tid];
            s1 += part[1][gg * QT + tid];
            s2 += part[2][gg * QT + tid];
            s3 += part[3][gg * QT + tid];
        }
        f32x4 m;
#pragma unroll
        for (int e = 0; e < 4; ++e)
            m[e] = fminf(fminf(s0[e], s1[e]), fminf(s2[e], s3[e]));
        atomicMin(sb + q * 4 + 0, __float_as_uint(m[0]));
        atomicMin(sb + q * 4 + 1, __float_as_uint(m[1]));
        atomicMin(sb + q * 4 + 2, __float_as_uint(m[2]));
        atomicMin(sb + q * 4 + 3, __float_as_uint(m[3]));
    }
}

__global__ __launch_bounds__(256)
void dist_min_kernel(const float* __restrict__ lib0, const float* __restrict__ fmap0,
                     const float* __restrict__ lib1, const float* __restrict__ fmap1,
                     const float* __restrict__ lib2, const float* __restrict__ fmap2,
                     const int* __restrict__ kp, const int* __restrict__ idx,
                     unsigned* __restrict__ sb0, unsigned* __restrict__ sb1,
                     unsigned* __restrict__ sb2) {
    __shared__ f32x4 part[4][256];
    const int k = *kp;
    const int nb = blockIdx.y * 4;
    if (nb >= k) return;
    int img[4];
#pragma unroll
    for (int j = 0; j < 4; ++j) {
        int n = nb + j;
        n = n < k ? n : k - 1;          // dup stream at tail: idempotent min
        img[j] = idx[n];
    }
    const int t = blockIdx.x;           // 0..23, pins to XCD t%8
    if (t < 13)      dist_min_level<256, 784, 64>(lib0, fmap0, img, t, sb0, part);       // 13 tiles
    else if (t < 20) dist_min_level<512, 196, 32>(lib1, fmap1, img, t - 13, sb1, part);  // 7 tiles
    else             dist_min_level<1024, 49, 16>(lib2, fmap2, img, t - 20, sb2, part);  // 4 tiles
}

// ---------------------------------------------------------------------------
// Kernel 4: bilinear upsample of sqrt(smin-bits) + sum + blur-H. (R5-proven)
// ---------------------------------------------------------------------------
static __device__ __forceinline__ void samp(int o, float inv_f, int sz, int& i0, int& i1,
                                            float& fr) {
    float c  = (o + 0.5f) * inv_f - 0.5f;   // inv_f power of two: exact
    float fl = floorf(c);
    fr = c - fl;
    int i = (int)fl;
    i0 = iclamp(i, 0, sz - 1);
    i1 = iclamp(i + 1, 0, sz - 1);
}

static __device__ __forceinline__ float ldsq(const unsigned* __restrict__ sb, int w, int y, int x) {
    return sqrtf(__uint_as_float(sb[y * w + x]));
}

static __device__ __forceinline__ float bilerp_sq(const unsigned* __restrict__ sb, int w,
                                                  int y0, int y1, int x0, int x1,
                                                  float fy, float fx) {
    float a = ldsq(sb, w, y0, x0), b = ldsq(sb, w, y0, x1);
    float c = ldsq(sb, w, y1, x0), d = ldsq(sb, w, y1, x1);
    float top = a + (b - a) * fx;
    float bot = c + (d - c) * fx;
    return top + (bot - top) * fy;
}

static __device__ __forceinline__ int reflect224(int i) {
    if (i < 0) i = -i;
    if (i > 223) i = 446 - i;
    return i;
}

static __device__ __forceinline__ void gauss_w(float* w) {
    float tot = 0.f;
#pragma unroll
    for (int j = 0; j < 17; ++j) {
        float t = (j - 8) * 0.25f;
        w[j] = expf(-0.5f * t * t);
        tot += w[j];
    }
    float inv = 1.f / tot;
#pragma unroll
    for (int j = 0; j < 17; ++j) w[j] *= inv;
}

__global__ __launch_bounds__(256)
void up_blurh_kernel(const unsigned* __restrict__ sb0, const unsigned* __restrict__ sb1,
                     const unsigned* __restrict__ sb2, float* __restrict__ tmp) {
    __shared__ float row[224];
    const int y = blockIdx.x, x = threadIdx.x;
    int y0, y1, x0, x1; float fy, fx;
    if (x < 224) {
        float v = 0.f;
        samp(y, 0.25f, 56, y0, y1, fy);   samp(x, 0.25f, 56, x0, x1, fx);
        v += bilerp_sq(sb0, 56, y0, y1, x0, x1, fy, fx);
        samp(y, 0.125f, 28, y0, y1, fy);  samp(x, 0.125f, 28, x0, x1, fx);
        v += bilerp_sq(sb1, 28, y0, y1, x0, x1, fy, fx);
        samp(y, 0.0625f, 14, y0, y1, fy); samp(x, 0.0625f, 14, x0, x1, fx);
        v += bilerp_sq(sb2, 14, y0, y1, x0, x1, fy, fx);
        row[x] = v;
    }
    __syncthreads();
    if (x < 224) {
        float w[17];
        gauss_w(w);
        float acc = 0.f;
#pragma unroll
        for (int j = 0; j < 17; ++j) acc += w[j] * row[reflect224(x + j - 8)];
        tmp[y * 224 + x] = acc;
    }
}

__global__ __launch_bounds__(256)
void blur_v_kernel(const float* __restrict__ in, float* __restrict__ out) {
    const int i = blockIdx.x * blockDim.x + threadIdx.x;
    if (i >= 224 * 224) return;
    const int y = i / 224, x = i % 224;
    float w[17];
    gauss_w(w);
    float acc = 0.f;
#pragma unroll
    for (int j = 0; j < 17; ++j) acc += w[j] * in[reflect224(y + j - 8) * 224 + x];
    out[i] = acc;
}

// ---------------------------------------------------------------------------
// Launch
// ---------------------------------------------------------------------------
extern "C" void kernel_launch(void* const* d_in, const int* in_sizes, int n_in,
                              void* d_out, int out_size, void* d_ws, size_t ws_size,
                              hipStream_t stream) {
    const float* z     = (const float*)d_in[0];
    const float* z_lib = (const float*)d_in[1];
    const float* fmap0 = (const float*)d_in[2];
    const float* fmap1 = (const float*)d_in[3];
    const float* fmap2 = (const float*)d_in[4];
    const float* lib0  = (const float*)d_in[5];
    const float* lib1  = (const float*)d_in[6];
    const float* lib2  = (const float*)d_in[7];
    const int*   kp    = (const int*)d_in[8];
    float* out = (float*)d_out;

    // workspace layout (16B aligned)
    constexpr size_t OFF_IDX   = 0;        // 128 i32
    constexpr size_t OFF_DIST2 = 1024;     // 128 f32
    constexpr size_t OFF_SB0   = 2048;     // 3136 u32
    constexpr size_t OFF_SB1   = 16384;    // 784 u32
    constexpr size_t OFF_SB2   = 20480;    // 196 u32
    constexpr size_t OFF_TMP   = 24576;    // 50176 f32

    char* ws = (char*)d_ws;
    int*      idx   = (int*)(ws + OFF_IDX);
    float*    dist2 = (float*)(ws + OFF_DIST2);
    unsigned* sb0   = (unsigned*)(ws + OFF_SB0);
    unsigned* sb1   = (unsigned*)(ws + OFF_SB1);
    unsigned* sb2   = (unsigned*)(ws + OFF_SB2);
    float*    tmp   = (float*)(ws + OFF_TMP);

    // 1) row distances + smin init
    row_dist_kernel<<<dim3(NLIB), dim3(256), 0, stream>>>(z, z_lib, dist2, sb0, sb1, sb2);
    // 2) rank-select + z_score
    select_kernel<<<dim3(1), dim3(128), 0, stream>>>(dist2, kp, out, idx);
    // 3) fused distances + min, 24 byte-uniform tiles, 4 n/block (reg-fmap reuse)
    dist_min_kernel<<<dim3(24, 32), dim3(256), 0, stream>>>(
        lib0, fmap0, lib1, fmap1, lib2, fmap2, kp, idx, sb0, sb1, sb2);
    // 4) upsample + sum + blur-H
    up_blurh_kernel<<<dim3(224), dim3(256), 0, stream>>>(sb0, sb1, sb2, tmp);
    // 5) blur-V
    blur_v_kernel<<<dim3(196), dim3(256), 0, stream>>>(tmp, out + 1);
}

// Round 10
// 83.397 us; speedup vs baseline: 1.7869x; 1.7869x over previous
//
#include <hip/hip_runtime.h>
#include <math.h>

#define NLIB 128
#define INFBITS 0x7F800000u

typedef float f32x4 __attribute__((ext_vector_type(4)));

static __device__ __forceinline__ int iclamp(int v, int lo, int hi) {
    return v < lo ? lo : (v > hi ? hi : v);
}

// ---------------------------------------------------------------------------
// Kernel 1: per-row squared distance ||z_lib[n]-z||^2 (128 blocks x 256 thr)
// + init of smin-bits buffers. (R5-proven)
// ---------------------------------------------------------------------------
__global__ __launch_bounds__(256)
void row_dist_kernel(const float* __restrict__ z, const float* __restrict__ z_lib,
                     float* __restrict__ dist2, unsigned* __restrict__ sb0,
                     unsigned* __restrict__ sb1, unsigned* __restrict__ sb2) {
    const int n = blockIdx.x;
    const int tid = threadIdx.x, wave = tid >> 6, lane = tid & 63;
    const int gid = n * 256 + tid;
    if (gid < 3136)      sb0[gid] = INFBITS;
    else if (gid < 3920) sb1[gid - 3136] = INFBITS;
    else if (gid < 4116) sb2[gid - 3920] = INFBITS;

    const f32x4 a = ((const f32x4*)(z_lib + (size_t)n * 1024))[tid];
    const f32x4 b = ((const f32x4*)z)[tid];
    f32x4 d = a - b;
    f32x4 s = d * d;
    float acc = s[0] + s[1] + s[2] + s[3];
    for (int off = 32; off > 0; off >>= 1) acc += __shfl_down(acc, off, 64);
    __shared__ float ws4[4];
    if (lane == 0) ws4[wave] = acc;
    __syncthreads();
    if (tid == 0) dist2[n] = ws4[0] + ws4[1] + ws4[2] + ws4[3];
}

// ---------------------------------------------------------------------------
// Kernel 2: FUSED select + dist + min. 48 byte-uniform tiles (128KB lib
// each; R5's proven 24-tile layout split in half for 2x TLP: 2400 active
// blocks, ~32 waves/CU). 48%8==0 -> tile t pins to XCD t%8, per-XCD bytes
// balanced, fmap slices L2/L3-resident. Each block recomputes its n's
// rank-select from dist2 in-block (deterministic, ~0.2us) — no idx buffer,
// no select launch. Block (0,0) also writes z_score. 1 n-stream per block
// (multi-stream regressed 3x: TLP loss). LDS-combine fixed order;
// atomicMin(uint bits). No NT hints (regressed twice).
// ---------------------------------------------------------------------------
template <int C, int NQ, int QT>
static __device__ __forceinline__ void dist_min_level(const float* __restrict__ lib,
                                                      const float* __restrict__ fmap,
                                                      int img, int qt,
                                                      unsigned* __restrict__ sb,
                                                      f32x4* __restrict__ part) {
    constexpr int G  = 256 / QT;       // channel groups per block
    constexpr int CW = C / G;          // channels per thread (= 32)
    const int tid = threadIdx.x;
    const int ql  = tid & (QT - 1);
    const int g   = tid / QT;
    const int q   = qt * QT + ql;
    const int qc  = q < NQ ? q : NQ - 1;     // clamp: dup same-address loads
    const f32x4* __restrict__ lp = (const f32x4*)lib + ((size_t)img * C + g * CW) * NQ + qc;
    const f32x4* __restrict__ fp = (const f32x4*)fmap + ((size_t)g * CW) * NQ + qc;
    f32x4 acc = {};
#pragma unroll 8
    for (int c = 0; c < CW; ++c) {
        f32x4 a = lp[(size_t)c * NQ];
        f32x4 f = fp[(size_t)c * NQ];
        f32x4 d = a - f;
        acc += d * d;
    }
    part[tid] = acc;
    __syncthreads();
    if (tid < QT && q < NQ) {
        f32x4 s = part[tid];
#pragma unroll
        for (int gg = 1; gg < G; ++gg) s += part[gg * QT + tid];  // fixed order
        atomicMin(sb + q * 4 + 0, __float_as_uint(s[0]));
        atomicMin(sb + q * 4 + 1, __float_as_uint(s[1]));
        atomicMin(sb + q * 4 + 2, __float_as_uint(s[2]));
        atomicMin(sb + q * 4 + 3, __float_as_uint(s[3]));
    }
}

__global__ __launch_bounds__(256)
void dist_min_kernel(const float* __restrict__ lib0, const float* __restrict__ fmap0,
                     const float* __restrict__ lib1, const float* __restrict__ fmap1,
                     const float* __restrict__ lib2, const float* __restrict__ fmap2,
                     const int* __restrict__ kp, const float* __restrict__ dist2,
                     float* __restrict__ zscore,
                     unsigned* __restrict__ sb0, unsigned* __restrict__ sb1,
                     unsigned* __restrict__ sb2) {
    __shared__ f32x4 part[256];
    __shared__ float dsh[NLIB];
    __shared__ float contrib[NLIB];
    __shared__ int img_sh;
    const int k = *kp;
    const int n = blockIdx.y;
    if (n >= k) return;
    const int tid = threadIdx.x;
    const int t = blockIdx.x;                 // 0..47, pins to XCD t%8

    // in-block rank-select: find image whose rank == n (deterministic)
    if (tid < NLIB) dsh[tid] = dist2[tid];
    __syncthreads();
    if (tid < NLIB) {
        const float dd = dsh[tid];
        int rank = 0;
#pragma unroll 8
        for (int m = 0; m < NLIB; ++m) {
            const float dm = dsh[m];
            rank += (dm < dd || (dm == dd && m < tid)) ? 1 : 0;
        }
        if (rank == n) img_sh = tid;
        if (t == 0 && n == 0) contrib[tid] = (rank < k) ? sqrtf(dd) : 0.f;
    }
    __syncthreads();
    if (t == 0 && n == 0 && tid == 0) {
        float s = 0.f;
        for (int m = 0; m < NLIB; ++m) s += contrib[m];   // fixed order
        zscore[0] = s / (float)k;
    }
    const int img = img_sh;

    if (t < 26)      dist_min_level<256, 784, 32>(lib0, fmap0, img, t, sb0, part);       // 26 tiles
    else if (t < 40) dist_min_level<512, 196, 16>(lib1, fmap1, img, t - 26, sb1, part);  // 14 tiles
    else             dist_min_level<1024, 49, 8>(lib2, fmap2, img, t - 40, sb2, part);   //  8 tiles
}

// ---------------------------------------------------------------------------
// Kernel 3: bilinear upsample of sqrt(smin-bits) + sum + blur-H. (R5-proven)
// ---------------------------------------------------------------------------
static __device__ __forceinline__ void samp(int o, float inv_f, int sz, int& i0, int& i1,
                                            float& fr) {
    float c  = (o + 0.5f) * inv_f - 0.5f;   // inv_f power of two: exact
    float fl = floorf(c);
    fr = c - fl;
    int i = (int)fl;
    i0 = iclamp(i, 0, sz - 1);
    i1 = iclamp(i + 1, 0, sz - 1);
}

static __device__ __forceinline__ float ldsq(const unsigned* __restrict__ sb, int w, int y, int x) {
    return sqrtf(__uint_as_float(sb[y * w + x]));
}

static __device__ __forceinline__ float bilerp_sq(const unsigned* __restrict__ sb, int w,
                                                  int y0, int y1, int x0, int x1,
                                                  float fy, float fx) {
    float a = ldsq(sb, w, y0, x0), b = ldsq(sb, w, y0, x1);
    float c = ldsq(sb, w, y1, x0), d = ldsq(sb, w, y1, x1);
    float top = a + (b - a) * fx;
    float bot = c + (d - c) * fx;
    return top + (bot - top) * fy;
}

static __device__ __forceinline__ int reflect224(int i) {
    if (i < 0) i = -i;
    if (i > 223) i = 446 - i;
    return i;
}

static __device__ __forceinline__ void gauss_w(float* w) {
    float tot = 0.f;
#pragma unroll
    for (int j = 0; j < 17; ++j) {
        float t = (j - 8) * 0.25f;
        w[j] = expf(-0.5f * t * t);
        tot += w[j];
    }
    float inv = 1.f / tot;
#pragma unroll
    for (int j = 0; j < 17; ++j) w[j] *= inv;
}

__global__ __launch_bounds__(256)
void up_blurh_kernel(const unsigned* __restrict__ sb0, const unsigned* __restrict__ sb1,
                     const unsigned* __restrict__ sb2, float* __restrict__ tmp) {
    __shared__ float row[224];
    const int y = blockIdx.x, x = threadIdx.x;
    int y0, y1, x0, x1; float fy, fx;
    if (x < 224) {
        float v = 0.f;
        samp(y, 0.25f, 56, y0, y1, fy);   samp(x, 0.25f, 56, x0, x1, fx);
        v += bilerp_sq(sb0, 56, y0, y1, x0, x1, fy, fx);
        samp(y, 0.125f, 28, y0, y1, fy);  samp(x, 0.125f, 28, x0, x1, fx);
        v += bilerp_sq(sb1, 28, y0, y1, x0, x1, fy, fx);
        samp(y, 0.0625f, 14, y0, y1, fy); samp(x, 0.0625f, 14, x0, x1, fx);
        v += bilerp_sq(sb2, 14, y0, y1, x0, x1, fy, fx);
        row[x] = v;
    }
    __syncthreads();
    if (x < 224) {
        float w[17];
        gauss_w(w);
        float acc = 0.f;
#pragma unroll
        for (int j = 0; j < 17; ++j) acc += w[j] * row[reflect224(x + j - 8)];
        tmp[y * 224 + x] = acc;
    }
}

__global__ __launch_bounds__(256)
void blur_v_kernel(const float* __restrict__ in, float* __restrict__ out) {
    const int i = blockIdx.x * blockDim.x + threadIdx.x;
    if (i >= 224 * 224) return;
    const int y = i / 224, x = i % 224;
    float w[17];
    gauss_w(w);
    float acc = 0.f;
#pragma unroll
    for (int j = 0; j < 17; ++j) acc += w[j] * in[reflect224(y + j - 8) * 224 + x];
    out[i] = acc;
}

// ---------------------------------------------------------------------------
// Launch
// ---------------------------------------------------------------------------
extern "C" void kernel_launch(void* const* d_in, const int* in_sizes, int n_in,
                              void* d_out, int out_size, void* d_ws, size_t ws_size,
                              hipStream_t stream) {
    const float* z     = (const float*)d_in[0];
    const float* z_lib = (const float*)d_in[1];
    const float* fmap0 = (const float*)d_in[2];
    const float* fmap1 = (const float*)d_in[3];
    const float* fmap2 = (const float*)d_in[4];
    const float* lib0  = (const float*)d_in[5];
    const float* lib1  = (const float*)d_in[6];
    const float* lib2  = (const float*)d_in[7];
    const int*   kp    = (const int*)d_in[8];
    float* out = (float*)d_out;

    // workspace layout (16B aligned)
    constexpr size_t OFF_DIST2 = 1024;     // 128 f32
    constexpr size_t OFF_SB0   = 2048;     // 3136 u32
    constexpr size_t OFF_SB1   = 16384;    // 784 u32
    constexpr size_t OFF_SB2   = 20480;    // 196 u32
    constexpr size_t OFF_TMP   = 24576;    // 50176 f32

    char* ws = (char*)d_ws;
    float*    dist2 = (float*)(ws + OFF_DIST2);
    unsigned* sb0   = (unsigned*)(ws + OFF_SB0);
    unsigned* sb1   = (unsigned*)(ws + OFF_SB1);
    unsigned* sb2   = (unsigned*)(ws + OFF_SB2);
    float*    tmp   = (float*)(ws + OFF_TMP);

    // 1) row distances + smin init
    row_dist_kernel<<<dim3(NLIB), dim3(256), 0, stream>>>(z, z_lib, dist2, sb0, sb1, sb2);
    // 2) fused select + distances + min, 48 byte-uniform tiles, 1 n/block
    dist_min_kernel<<<dim3(48, NLIB), dim3(256), 0, stream>>>(
        lib0, fmap0, lib1, fmap1, lib2, fmap2, kp, dist2, out, sb0, sb1, sb2);
    // 3) upsample + sum + blur-H
    up_blurh_kernel<<<dim3(224), dim3(256), 0, stream>>>(sb0, sb1, sb2, tmp);
    // 4) blur-V
    blur_v_kernel<<<dim3(196), dim3(256), 0, stream>>>(tmp, out + 1);
}

// Round 11
// 81.152 us; speedup vs baseline: 1.8363x; 1.0277x over previous
//
#include <hip/hip_runtime.h>
#include <math.h>

#define NLIB 128
#define INFBITS 0x7F800000u

typedef float f32x4 __attribute__((ext_vector_type(4)));

static __device__ __forceinline__ int iclamp(int v, int lo, int hi) {
    return v < lo ? lo : (v > hi ? hi : v);
}

// ---------------------------------------------------------------------------
// Kernel 1: per-row squared distance ||z_lib[n]-z||^2 (128 blocks x 256 thr)
// + init of smin-bits buffers. (R5-proven)
// ---------------------------------------------------------------------------
__global__ __launch_bounds__(256)
void row_dist_kernel(const float* __restrict__ z, const float* __restrict__ z_lib,
                     float* __restrict__ dist2, unsigned* __restrict__ sb0,
                     unsigned* __restrict__ sb1, unsigned* __restrict__ sb2) {
    const int n = blockIdx.x;
    const int tid = threadIdx.x, wave = tid >> 6, lane = tid & 63;
    const int gid = n * 256 + tid;
    if (gid < 3136)      sb0[gid] = INFBITS;
    else if (gid < 3920) sb1[gid - 3136] = INFBITS;
    else if (gid < 4116) sb2[gid - 3920] = INFBITS;

    const f32x4 a = ((const f32x4*)(z_lib + (size_t)n * 1024))[tid];
    const f32x4 b = ((const f32x4*)z)[tid];
    f32x4 d = a - b;
    f32x4 s = d * d;
    float acc = s[0] + s[1] + s[2] + s[3];
    for (int off = 32; off > 0; off >>= 1) acc += __shfl_down(acc, off, 64);
    __shared__ float ws4[4];
    if (lane == 0) ws4[wave] = acc;
    __syncthreads();
    if (tid == 0) dist2[n] = ws4[0] + ws4[1] + ws4[2] + ws4[3];
}

// ---------------------------------------------------------------------------
// Kernel 2: FUSED select + dist + min. 48 byte-uniform tiles, 2 n per block
// -> 48 x 25 = 1200 active blocks (same TLP as the proven R5 config) while
// halving fmap VMEM issue slots (one fmap load feeds two lib streams).
// 48%8==0 -> tile t pins to XCD t%8, per-XCD bytes balanced. In-block
// rank-select (deterministic); block (0,0) writes z_score. No NT hints.
// LDS-combine fixed order; min over the 2 images; atomicMin(uint bits).
// ---------------------------------------------------------------------------
template <int C, int NQ, int QT>
static __device__ __forceinline__ void dist_min_level(const float* __restrict__ lib,
                                                      const float* __restrict__ fmap,
                                                      int img0, int img1, int qt,
                                                      unsigned* __restrict__ sb,
                                                      f32x4 (* __restrict__ part)[256]) {
    constexpr int G  = 256 / QT;       // channel groups per block
    constexpr int CW = C / G;          // channels per thread (= 32)
    const int tid = threadIdx.x;
    const int ql  = tid & (QT - 1);
    const int g   = tid / QT;
    const int q   = qt * QT + ql;
    const int qc  = q < NQ ? q : NQ - 1;     // clamp: dup same-address loads
    const f32x4* __restrict__ lp0 = (const f32x4*)lib + ((size_t)img0 * C + g * CW) * NQ + qc;
    const f32x4* __restrict__ lp1 = (const f32x4*)lib + ((size_t)img1 * C + g * CW) * NQ + qc;
    const f32x4* __restrict__ fp  = (const f32x4*)fmap + ((size_t)g * CW) * NQ + qc;
    f32x4 acc0 = {}, acc1 = {};
#pragma unroll 8
    for (int c = 0; c < CW; ++c) {
        f32x4 f  = fp[(size_t)c * NQ];
        f32x4 a0 = lp0[(size_t)c * NQ];
        f32x4 a1 = lp1[(size_t)c * NQ];
        f32x4 d0 = a0 - f;
        f32x4 d1 = a1 - f;
        acc0 += d0 * d0;
        acc1 += d1 * d1;
    }
    part[0][tid] = acc0;
    part[1][tid] = acc1;
    __syncthreads();
    if (tid < QT && q < NQ) {
        f32x4 s0 = part[0][tid];
        f32x4 s1 = part[1][tid];
#pragma unroll
        for (int gg = 1; gg < G; ++gg) {            // fixed ascending g order
            s0 += part[0][gg * QT + tid];
            s1 += part[1][gg * QT + tid];
        }
        f32x4 m;
#pragma unroll
        for (int e = 0; e < 4; ++e) m[e] = fminf(s0[e], s1[e]);
        atomicMin(sb + q * 4 + 0, __float_as_uint(m[0]));
        atomicMin(sb + q * 4 + 1, __float_as_uint(m[1]));
        atomicMin(sb + q * 4 + 2, __float_as_uint(m[2]));
        atomicMin(sb + q * 4 + 3, __float_as_uint(m[3]));
    }
}

__global__ __launch_bounds__(256)
void dist_min_kernel(const float* __restrict__ lib0, const float* __restrict__ fmap0,
                     const float* __restrict__ lib1, const float* __restrict__ fmap1,
                     const float* __restrict__ lib2, const float* __restrict__ fmap2,
                     const int* __restrict__ kp, const float* __restrict__ dist2,
                     float* __restrict__ zscore,
                     unsigned* __restrict__ sb0, unsigned* __restrict__ sb1,
                     unsigned* __restrict__ sb2) {
    __shared__ f32x4 part[2][256];
    __shared__ float dsh[NLIB];
    __shared__ float contrib[NLIB];
    __shared__ int img0_sh, img1_sh;
    const int k = *kp;
    const int n0 = blockIdx.y * 2;
    if (n0 >= k) return;
    const int n1 = (n0 + 1 < k) ? n0 + 1 : k - 1;   // dup stream if k odd
    const int tid = threadIdx.x;
    const int t = blockIdx.x;                 // 0..47, pins to XCD t%8

    // in-block rank-select: find images whose ranks == n0, n1 (deterministic)
    if (tid < NLIB) dsh[tid] = dist2[tid];
    __syncthreads();
    if (tid < NLIB) {
        const float dd = dsh[tid];
        int rank = 0;
#pragma unroll 8
        for (int m = 0; m < NLIB; ++m) {
            const float dm = dsh[m];
            rank += (dm < dd || (dm == dd && m < tid)) ? 1 : 0;
        }
        if (rank == n0) img0_sh = tid;
        if (rank == n1) img1_sh = tid;
        if (t == 0 && n0 == 0) contrib[tid] = (rank < k) ? sqrtf(dd) : 0.f;
    }
    __syncthreads();
    if (t == 0 && n0 == 0 && tid == 0) {
        float s = 0.f;
        for (int m = 0; m < NLIB; ++m) s += contrib[m];   // fixed order
        zscore[0] = s / (float)k;
    }
    const int img0 = img0_sh, img1 = img1_sh;

    if (t < 26)      dist_min_level<256, 784, 32>(lib0, fmap0, img0, img1, t, sb0, part);       // 26 tiles
    else if (t < 40) dist_min_level<512, 196, 16>(lib1, fmap1, img0, img1, t - 26, sb1, part);  // 14 tiles
    else             dist_min_level<1024, 49, 8>(lib2, fmap2, img0, img1, t - 40, sb2, part);   //  8 tiles
}

// ---------------------------------------------------------------------------
// Kernel 3: bilinear upsample of sqrt(smin-bits) + sum + blur-H. (R5-proven)
// ---------------------------------------------------------------------------
static __device__ __forceinline__ void samp(int o, float inv_f, int sz, int& i0, int& i1,
                                            float& fr) {
    float c  = (o + 0.5f) * inv_f - 0.5f;   // inv_f power of two: exact
    float fl = floorf(c);
    fr = c - fl;
    int i = (int)fl;
    i0 = iclamp(i, 0, sz - 1);
    i1 = iclamp(i + 1, 0, sz - 1);
}

static __device__ __forceinline__ float ldsq(const unsigned* __restrict__ sb, int w, int y, int x) {
    return sqrtf(__uint_as_float(sb[y * w + x]));
}

static __device__ __forceinline__ float bilerp_sq(const unsigned* __restrict__ sb, int w,
                                                  int y0, int y1, int x0, int x1,
                                                  float fy, float fx) {
    float a = ldsq(sb, w, y0, x0), b = ldsq(sb, w, y0, x1);
    float c = ldsq(sb, w, y1, x0), d = ldsq(sb, w, y1, x1);
    float top = a + (b - a) * fx;
    float bot = c + (d - c) * fx;
    return top + (bot - top) * fy;
}

static __device__ __forceinline__ int reflect224(int i) {
    if (i < 0) i = -i;
    if (i > 223) i = 446 - i;
    return i;
}

static __device__ __forceinline__ void gauss_w(float* w) {
    float tot = 0.f;
#pragma unroll
    for (int j = 0; j < 17; ++j) {
        float t = (j - 8) * 0.25f;
        w[j] = expf(-0.5f * t * t);
        tot += w[j];
    }
    float inv = 1.f / tot;
#pragma unroll
    for (int j = 0; j < 17; ++j) w[j] *= inv;
}

__global__ __launch_bounds__(256)
void up_blurh_kernel(const unsigned* __restrict__ sb0, const unsigned* __restrict__ sb1,
                     const unsigned* __restrict__ sb2, float* __restrict__ tmp) {
    __shared__ float row[224];
    const int y = blockIdx.x, x = threadIdx.x;
    int y0, y1, x0, x1; float fy, fx;
    if (x < 224) {
        float v = 0.f;
        samp(y, 0.25f, 56, y0, y1, fy);   samp(x, 0.25f, 56, x0, x1, fx);
        v += bilerp_sq(sb0, 56, y0, y1, x0, x1, fy, fx);
        samp(y, 0.125f, 28, y0, y1, fy);  samp(x, 0.125f, 28, x0, x1, fx);
        v += bilerp_sq(sb1, 28, y0, y1, x0, x1, fy, fx);
        samp(y, 0.0625f, 14, y0, y1, fy); samp(x, 0.0625f, 14, x0, x1, fx);
        v += bilerp_sq(sb2, 14, y0, y1, x0, x1, fy, fx);
        row[x] = v;
    }
    __syncthreads();
    if (x < 224) {
        float w[17];
        gauss_w(w);
        float acc = 0.f;
#pragma unroll
        for (int j = 0; j < 17; ++j) acc += w[j] * row[reflect224(x + j - 8)];
        tmp[y * 224 + x] = acc;
    }
}

__global__ __launch_bounds__(256)
void blur_v_kernel(const float* __restrict__ in, float* __restrict__ out) {
    const int i = blockIdx.x * blockDim.x + threadIdx.x;
    if (i >= 224 * 224) return;
    const int y = i / 224, x = i % 224;
    float w[17];
    gauss_w(w);
    float acc = 0.f;
#pragma unroll
    for (int j = 0; j < 17; ++j) acc += w[j] * in[reflect224(y + j - 8) * 224 + x];
    out[i] = acc;
}

// ---------------------------------------------------------------------------
// Launch
// ---------------------------------------------------------------------------
extern "C" void kernel_launch(void* const* d_in, const int* in_sizes, int n_in,
                              void* d_out, int out_size, void* d_ws, size_t ws_size,
                              hipStream_t stream) {
    const float* z     = (const float*)d_in[0];
    const float* z_lib = (const float*)d_in[1];
    const float* fmap0 = (const float*)d_in[2];
    const float* fmap1 = (const float*)d_in[3];
    const float* fmap2 = (const float*)d_in[4];
    const float* lib0  = (const float*)d_in[5];
    const float* lib1  = (const float*)d_in[6];
    const float* lib2  = (const float*)d_in[7];
    const int*   kp    = (const int*)d_in[8];
    float* out = (float*)d_out;

    // workspace layout (16B aligned)
    constexpr size_t OFF_DIST2 = 1024;     // 128 f32
    constexpr size_t OFF_SB0   = 2048;     // 3136 u32
    constexpr size_t OFF_SB1   = 16384;    // 784 u32
    constexpr size_t OFF_SB2   = 20480;    // 196 u32
    constexpr size_t OFF_TMP   = 24576;    // 50176 f32

    char* ws = (char*)d_ws;
    float*    dist2 = (float*)(ws + OFF_DIST2);
    unsigned* sb0   = (unsigned*)(ws + OFF_SB0);
    unsigned* sb1   = (unsigned*)(ws + OFF_SB1);
    unsigned* sb2   = (unsigned*)(ws + OFF_SB2);
    float*    tmp   = (float*)(ws + OFF_TMP);

    // 1) row distances + smin init
    row_dist_kernel<<<dim3(NLIB), dim3(256), 0, stream>>>(z, z_lib, dist2, sb0, sb1, sb2);
    // 2) fused select + distances + min, 48 tiles x 2 n/block (1200 blocks)
    dist_min_kernel<<<dim3(48, 64), dim3(256), 0, stream>>>(
        lib0, fmap0, lib1, fmap1, lib2, fmap2, kp, dist2, out, sb0, sb1, sb2);
    // 3) upsample + sum + blur-H
    up_blurh_kernel<<<dim3(224), dim3(256), 0, stream>>>(sb0, sb1, sb2, tmp);
    // 4) blur-V
    blur_v_kernel<<<dim3(196), dim3(256), 0, stream>>>(tmp, out + 1);
}

// Round 12
// 80.645 us; speedup vs baseline: 1.8478x; 1.0063x over previous
//
#include <hip/hip_runtime.h>
#include <math.h>

#define NLIB 128
#define INFBITS 0x7F800000u

typedef float f32x4 __attribute__((ext_vector_type(4)));

static __device__ __forceinline__ int iclamp(int v, int lo, int hi) {
    return v < lo ? lo : (v > hi ? hi : v);
}

// ---------------------------------------------------------------------------
// Kernel 1: per-row squared distance ||z_lib[n]-z||^2 (128 blocks x 256 thr)
// + init of smin-bits buffers. (R5-proven)
// ---------------------------------------------------------------------------
__global__ __launch_bounds__(256)
void row_dist_kernel(const float* __restrict__ z, const float* __restrict__ z_lib,
                     float* __restrict__ dist2, unsigned* __restrict__ sb0,
                     unsigned* __restrict__ sb1, unsigned* __restrict__ sb2) {
    const int n = blockIdx.x;
    const int tid = threadIdx.x, wave = tid >> 6, lane = tid & 63;
    const int gid = n * 256 + tid;
    if (gid < 3136)      sb0[gid] = INFBITS;
    else if (gid < 3920) sb1[gid - 3136] = INFBITS;
    else if (gid < 4116) sb2[gid - 3920] = INFBITS;

    const f32x4 a = ((const f32x4*)(z_lib + (size_t)n * 1024))[tid];
    const f32x4 b = ((const f32x4*)z)[tid];
    f32x4 d = a - b;
    f32x4 s = d * d;
    float acc = s[0] + s[1] + s[2] + s[3];
    for (int off = 32; off > 0; off >>= 1) acc += __shfl_down(acc, off, 64);
    __shared__ float ws4[4];
    if (lane == 0) ws4[wave] = acc;
    __syncthreads();
    if (tid == 0) dist2[n] = ws4[0] + ws4[1] + ws4[2] + ws4[3];
}

// ---------------------------------------------------------------------------
// Kernel 2: FUSED select + dist + min. 48 byte-uniform tiles, 2 n per block
// (1200 active blocks — proven TLP). Inner loop reordered into 8-channel
// bursts: 16 HBM lib loads issued FIRST, then 8 L2-hit fmap loads, then
// consume — keeps the HBM stream pipeline from stalling behind interleaved
// fmap waits. Accumulation order unchanged (ascending c) -> bitwise same.
// 48%8==0 -> tile t pins to XCD t%8, per-XCD bytes balanced. In-block
// rank-select (deterministic); block (0,0) writes z_score.
// ---------------------------------------------------------------------------
template <int C, int NQ, int QT>
static __device__ __forceinline__ void dist_min_level(const float* __restrict__ lib,
                                                      const float* __restrict__ fmap,
                                                      int img0, int img1, int qt,
                                                      unsigned* __restrict__ sb,
                                                      f32x4 (* __restrict__ part)[256]) {
    constexpr int G  = 256 / QT;       // channel groups per block
    constexpr int CW = C / G;          // channels per thread (= 32)
    const int tid = threadIdx.x;
    const int ql  = tid & (QT - 1);
    const int g   = tid / QT;
    const int q   = qt * QT + ql;
    const int qc  = q < NQ ? q : NQ - 1;     // clamp: dup same-address loads
    const f32x4* __restrict__ lp0 = (const f32x4*)lib + ((size_t)img0 * C + g * CW) * NQ + qc;
    const f32x4* __restrict__ lp1 = (const f32x4*)lib + ((size_t)img1 * C + g * CW) * NQ + qc;
    const f32x4* __restrict__ fp  = (const f32x4*)fmap + ((size_t)g * CW) * NQ + qc;
    f32x4 acc0 = {}, acc1 = {};
#pragma unroll
    for (int cc = 0; cc < CW / 8; ++cc) {
        f32x4 A0[8], A1[8], F[8];
#pragma unroll
        for (int u = 0; u < 8; ++u) A0[u] = lp0[(size_t)(cc * 8 + u) * NQ];   // HBM burst
#pragma unroll
        for (int u = 0; u < 8; ++u) A1[u] = lp1[(size_t)(cc * 8 + u) * NQ];   // HBM burst
#pragma unroll
        for (int u = 0; u < 8; ++u) F[u]  = fp[(size_t)(cc * 8 + u) * NQ];    // L2 hits
#pragma unroll
        for (int u = 0; u < 8; ++u) {
            f32x4 d0 = A0[u] - F[u]; acc0 += d0 * d0;
            f32x4 d1 = A1[u] - F[u]; acc1 += d1 * d1;
        }
    }
    part[0][tid] = acc0;
    part[1][tid] = acc1;
    __syncthreads();
    if (tid < QT && q < NQ) {
        f32x4 s0 = part[0][tid];
        f32x4 s1 = part[1][tid];
#pragma unroll
        for (int gg = 1; gg < G; ++gg) {            // fixed ascending g order
            s0 += part[0][gg * QT + tid];
            s1 += part[1][gg * QT + tid];
        }
        f32x4 m;
#pragma unroll
        for (int e = 0; e < 4; ++e) m[e] = fminf(s0[e], s1[e]);
        atomicMin(sb + q * 4 + 0, __float_as_uint(m[0]));
        atomicMin(sb + q * 4 + 1, __float_as_uint(m[1]));
        atomicMin(sb + q * 4 + 2, __float_as_uint(m[2]));
        atomicMin(sb + q * 4 + 3, __float_as_uint(m[3]));
    }
}

__global__ __launch_bounds__(256)
void dist_min_kernel(const float* __restrict__ lib0, const float* __restrict__ fmap0,
                     const float* __restrict__ lib1, const float* __restrict__ fmap1,
                     const float* __restrict__ lib2, const float* __restrict__ fmap2,
                     const int* __restrict__ kp, const float* __restrict__ dist2,
                     float* __restrict__ zscore,
                     unsigned* __restrict__ sb0, unsigned* __restrict__ sb1,
                     unsigned* __restrict__ sb2) {
    __shared__ f32x4 part[2][256];
    __shared__ float dsh[NLIB];
    __shared__ float contrib[NLIB];
    __shared__ int img0_sh, img1_sh;
    const int k = *kp;
    const int n0 = blockIdx.y * 2;
    if (n0 >= k) return;
    const int n1 = (n0 + 1 < k) ? n0 + 1 : k - 1;   // dup stream if k odd
    const int tid = threadIdx.x;
    const int t = blockIdx.x;                 // 0..47, pins to XCD t%8

    // in-block rank-select: find images whose ranks == n0, n1 (deterministic)
    if (tid < NLIB) dsh[tid] = dist2[tid];
    __syncthreads();
    if (tid < NLIB) {
        const float dd = dsh[tid];
        int rank = 0;
#pragma unroll 8
        for (int m = 0; m < NLIB; ++m) {
            const float dm = dsh[m];
            rank += (dm < dd || (dm == dd && m < tid)) ? 1 : 0;
        }
        if (rank == n0) img0_sh = tid;
        if (rank == n1) img1_sh = tid;
        if (t == 0 && n0 == 0) contrib[tid] = (rank < k) ? sqrtf(dd) : 0.f;
    }
    __syncthreads();
    if (t == 0 && n0 == 0 && tid == 0) {
        float s = 0.f;
        for (int m = 0; m < NLIB; ++m) s += contrib[m];   // fixed order
        zscore[0] = s / (float)k;
    }
    const int img0 = img0_sh, img1 = img1_sh;

    if (t < 26)      dist_min_level<256, 784, 32>(lib0, fmap0, img0, img1, t, sb0, part);       // 26 tiles
    else if (t < 40) dist_min_level<512, 196, 16>(lib1, fmap1, img0, img1, t - 26, sb1, part);  // 14 tiles
    else             dist_min_level<1024, 49, 8>(lib2, fmap2, img0, img1, t - 40, sb2, part);   //  8 tiles
}

// ---------------------------------------------------------------------------
// Kernel 3: bilinear upsample of sqrt(smin-bits) + sum + blur-H. (R5-proven)
// ---------------------------------------------------------------------------
static __device__ __forceinline__ void samp(int o, float inv_f, int sz, int& i0, int& i1,
                                            float& fr) {
    float c  = (o + 0.5f) * inv_f - 0.5f;   // inv_f power of two: exact
    float fl = floorf(c);
    fr = c - fl;
    int i = (int)fl;
    i0 = iclamp(i, 0, sz - 1);
    i1 = iclamp(i + 1, 0, sz - 1);
}

static __device__ __forceinline__ float ldsq(const unsigned* __restrict__ sb, int w, int y, int x) {
    return sqrtf(__uint_as_float(sb[y * w + x]));
}

static __device__ __forceinline__ float bilerp_sq(const unsigned* __restrict__ sb, int w,
                                                  int y0, int y1, int x0, int x1,
                                                  float fy, float fx) {
    float a = ldsq(sb, w, y0, x0), b = ldsq(sb, w, y0, x1);
    float c = ldsq(sb, w, y1, x0), d = ldsq(sb, w, y1, x1);
    float top = a + (b - a) * fx;
    float bot = c + (d - c) * fx;
    return top + (bot - top) * fy;
}

static __device__ __forceinline__ int reflect224(int i) {
    if (i < 0) i = -i;
    if (i > 223) i = 446 - i;
    return i;
}

static __device__ __forceinline__ void gauss_w(float* w) {
    float tot = 0.f;
#pragma unroll
    for (int j = 0; j < 17; ++j) {
        float t = (j - 8) * 0.25f;
        w[j] = expf(-0.5f * t * t);
        tot += w[j];
    }
    float inv = 1.f / tot;
#pragma unroll
    for (int j = 0; j < 17; ++j) w[j] *= inv;
}

__global__ __launch_bounds__(256)
void up_blurh_kernel(const unsigned* __restrict__ sb0, const unsigned* __restrict__ sb1,
                     const unsigned* __restrict__ sb2, float* __restrict__ tmp) {
    __shared__ float row[224];
    const int y = blockIdx.x, x = threadIdx.x;
    int y0, y1, x0, x1; float fy, fx;
    if (x < 224) {
        float v = 0.f;
        samp(y, 0.25f, 56, y0, y1, fy);   samp(x, 0.25f, 56, x0, x1, fx);
        v += bilerp_sq(sb0, 56, y0, y1, x0, x1, fy, fx);
        samp(y, 0.125f, 28, y0, y1, fy);  samp(x, 0.125f, 28, x0, x1, fx);
        v += bilerp_sq(sb1, 28, y0, y1, x0, x1, fy, fx);
        samp(y, 0.0625f, 14, y0, y1, fy); samp(x, 0.0625f, 14, x0, x1, fx);
        v += bilerp_sq(sb2, 14, y0, y1, x0, x1, fy, fx);
        row[x] = v;
    }
    __syncthreads();
    if (x < 224) {
        float w[17];
        gauss_w(w);
        float acc = 0.f;
#pragma unroll
        for (int j = 0; j < 17; ++j) acc += w[j] * row[reflect224(x + j - 8)];
        tmp[y * 224 + x] = acc;
    }
}

__global__ __launch_bounds__(256)
void blur_v_kernel(const float* __restrict__ in, float* __restrict__ out) {
    const int i = blockIdx.x * blockDim.x + threadIdx.x;
    if (i >= 224 * 224) return;
    const int y = i / 224, x = i % 224;
    float w[17];
    gauss_w(w);
    float acc = 0.f;
#pragma unroll
    for (int j = 0; j < 17; ++j) acc += w[j] * in[reflect224(y + j - 8) * 224 + x];
    out[i] = acc;
}

// ---------------------------------------------------------------------------
// Launch
// ---------------------------------------------------------------------------
extern "C" void kernel_launch(void* const* d_in, const int* in_sizes, int n_in,
                              void* d_out, int out_size, void* d_ws, size_t ws_size,
                              hipStream_t stream) {
    const float* z     = (const float*)d_in[0];
    const float* z_lib = (const float*)d_in[1];
    const float* fmap0 = (const float*)d_in[2];
    const float* fmap1 = (const float*)d_in[3];
    const float* fmap2 = (const float*)d_in[4];
    const float* lib0  = (const float*)d_in[5];
    const float* lib1  = (const float*)d_in[6];
    const float* lib2  = (const float*)d_in[7];
    const int*   kp    = (const int*)d_in[8];
    float* out = (float*)d_out;

    // workspace layout (16B aligned)
    constexpr size_t OFF_DIST2 = 1024;     // 128 f32
    constexpr size_t OFF_SB0   = 2048;     // 3136 u32
    constexpr size_t OFF_SB1   = 16384;    // 784 u32
    constexpr size_t OFF_SB2   = 20480;    // 196 u32
    constexpr size_t OFF_TMP   = 24576;    // 50176 f32

    char* ws = (char*)d_ws;
    float*    dist2 = (float*)(ws + OFF_DIST2);
    unsigned* sb0   = (unsigned*)(ws + OFF_SB0);
    unsigned* sb1   = (unsigned*)(ws + OFF_SB1);
    unsigned* sb2   = (unsigned*)(ws + OFF_SB2);
    float*    tmp   = (float*)(ws + OFF_TMP);

    // 1) row distances + smin init
    row_dist_kernel<<<dim3(NLIB), dim3(256), 0, stream>>>(z, z_lib, dist2, sb0, sb1, sb2);
    // 2) fused select + distances + min, 48 tiles x 2 n/block (1200 blocks)
    dist_min_kernel<<<dim3(48, 64), dim3(256), 0, stream>>>(
        lib0, fmap0, lib1, fmap1, lib2, fmap2, kp, dist2, out, sb0, sb1, sb2);
    // 3) upsample + sum + blur-H
    up_blurh_kernel<<<dim3(224), dim3(256), 0, stream>>>(sb0, sb1, sb2, tmp);
    // 4) blur-V
    blur_v_kernel<<<dim3(196), dim3(256), 0, stream>>>(tmp, out + 1);
}